// Round 1
// baseline (449.378 us; speedup 1.0000x reference)
//
#include <hip/hip_runtime.h>

// Scatter-add (segment_sum): out[tags[row]] += data[row] for 32768 rows of D=1024 fp32.
// Strategy: memset out to 0, then one float4-load + 4 atomicAdd per thread-iter.
// Fan-in avg = 2 rows/segment -> negligible atomic contention.

__global__ void combine_scatter_add(const float* __restrict__ data,
                                    const int* __restrict__ tags,
                                    float* __restrict__ out,
                                    long total_elems, int D_log2, int D_mask) {
    long stride = (long)gridDim.x * blockDim.x * 4L;
    for (long i = ((long)blockIdx.x * blockDim.x + threadIdx.x) * 4L;
         i < total_elems; i += stride) {
        float4 v = *reinterpret_cast<const float4*>(data + i);
        long row = i >> D_log2;
        int col = (int)(i & D_mask);
        int tag = tags[row];
        float* dst = out + ((long)tag << D_log2) + col;
        atomicAdd(dst + 0, v.x);
        atomicAdd(dst + 1, v.y);
        atomicAdd(dst + 2, v.z);
        atomicAdd(dst + 3, v.w);
    }
}

extern "C" void kernel_launch(void* const* d_in, const int* in_sizes, int n_in,
                              void* d_out, int out_size, void* d_ws, size_t ws_size,
                              hipStream_t stream) {
    const float* data = (const float*)d_in[0];
    const int* tags = (const int*)d_in[1];
    float* out = (float*)d_out;

    long total = (long)in_sizes[0];          // P*N*D = 33554432
    long n_rows = (long)in_sizes[1];         // P*N   = 32768
    int D = (int)(total / n_rows);           // 1024
    // D is a power of two (1024)
    int D_log2 = 0;
    while ((1 << D_log2) < D) ++D_log2;
    int D_mask = D - 1;

    // Output must be zeroed every call (harness doesn't re-poison between replays).
    hipMemsetAsync(d_out, 0, (size_t)out_size * sizeof(float), stream);

    const int block = 256;
    const int grid = 2048;  // grid-stride; ~8 blocks/CU worth of waves
    combine_scatter_add<<<grid, block, 0, stream>>>(data, tags, out, total, D_log2, D_mask);
}

// Round 2
// 43.270 us; speedup vs baseline: 10.3855x; 10.3855x over previous
//
#include <hip/hip_runtime.h>

// Segment-sum via GATHER instead of scatter-atomics.
// Round-1 post-mortem: atomicAdd path was L2-atomic-throughput-bound
// (WRITE_SIZE=512MB for 64MB out, 17% HBM BW). Here we build an inverted
// index (tag -> contributing rows) with cheap int atomics (32768 of them),
// then one block per output segment sums its ~2 contributor rows and writes
// once. No float atomics; data read 128MiB + out write 64MiB, all coalesced.

#define CAP 32          // slot capacity per segment; Poisson(2) tail beyond 32 ~ 1e-26
#define N_SEG 16384
#define DDIM 1024

__global__ void hist_fill(const int* __restrict__ tags, int n_rows,
                          int* __restrict__ counts,
                          unsigned short* __restrict__ slots) {
    int r = blockIdx.x * blockDim.x + threadIdx.x;
    if (r < n_rows) {
        int t = tags[r];
        int pos = atomicAdd(&counts[t], 1);
        if (pos < CAP) slots[(long)t * CAP + pos] = (unsigned short)r;
    }
}

__global__ void gather_sum(const float* __restrict__ data,
                           const int* __restrict__ tags,
                           const int* __restrict__ counts,
                           const unsigned short* __restrict__ slots,
                           float* __restrict__ out,
                           int n_rows) {
    int s = blockIdx.x;                 // segment id, one block per output row
    int col = threadIdx.x * 4;          // 256 threads x float4 = 1024 cols
    int k = counts[s];
    float4 acc = {0.f, 0.f, 0.f, 0.f};

    if (k <= CAP) {
        const unsigned short* sl = slots + (long)s * CAP;
        for (int j = 0; j < k; ++j) {
            int row = sl[j];
            float4 v = *reinterpret_cast<const float4*>(data + (long)row * DDIM + col);
            acc.x += v.x; acc.y += v.y; acc.z += v.z; acc.w += v.w;
        }
    } else {
        // Overflow fallback (deterministic, essentially never taken): slots
        // hold an arbitrary subset, so recompute the whole segment by scanning
        // all tags (L2-resident broadcast reads).
        for (int r = 0; r < n_rows; ++r) {
            if (tags[r] == s) {
                float4 v = *reinterpret_cast<const float4*>(data + (long)r * DDIM + col);
                acc.x += v.x; acc.y += v.y; acc.z += v.z; acc.w += v.w;
            }
        }
    }
    *reinterpret_cast<float4*>(out + (long)s * DDIM + col) = acc;
}

// Round-1 fallback kernel (used only if ws_size is too small for the index).
__global__ void combine_scatter_add(const float* __restrict__ data,
                                    const int* __restrict__ tags,
                                    float* __restrict__ out,
                                    long total_elems) {
    long stride = (long)gridDim.x * blockDim.x * 4L;
    for (long i = ((long)blockIdx.x * blockDim.x + threadIdx.x) * 4L;
         i < total_elems; i += stride) {
        float4 v = *reinterpret_cast<const float4*>(data + i);
        long row = i >> 10;
        int col = (int)(i & 1023);
        int tag = tags[row];
        float* dst = out + ((long)tag << 10) + col;
        atomicAdd(dst + 0, v.x);
        atomicAdd(dst + 1, v.y);
        atomicAdd(dst + 2, v.z);
        atomicAdd(dst + 3, v.w);
    }
}

extern "C" void kernel_launch(void* const* d_in, const int* in_sizes, int n_in,
                              void* d_out, int out_size, void* d_ws, size_t ws_size,
                              hipStream_t stream) {
    const float* data = (const float*)d_in[0];
    const int* tags = (const int*)d_in[1];
    float* out = (float*)d_out;

    long total = (long)in_sizes[0];   // 33554432
    int n_rows = in_sizes[1];         // 32768

    size_t counts_bytes = (size_t)N_SEG * sizeof(int);                 // 64 KiB
    size_t slots_bytes = (size_t)N_SEG * CAP * sizeof(unsigned short); // 1 MiB
    size_t need = counts_bytes + slots_bytes;

    if (ws_size < need) {
        // Safety net: shouldn't happen, but stay correct.
        hipMemsetAsync(d_out, 0, (size_t)out_size * sizeof(float), stream);
        combine_scatter_add<<<2048, 256, 0, stream>>>(data, tags, out, total);
        return;
    }

    int* counts = (int*)d_ws;
    unsigned short* slots = (unsigned short*)((char*)d_ws + counts_bytes);

    hipMemsetAsync(counts, 0, counts_bytes, stream);

    hist_fill<<<(n_rows + 255) / 256, 256, 0, stream>>>(tags, n_rows, counts, slots);

    gather_sum<<<N_SEG, 256, 0, stream>>>(data, tags, counts, slots, out, n_rows);
}